// Round 2
// baseline (2021.313 us; speedup 1.0000x reference)
//
#include <hip/hip_runtime.h>
#include <hip/hip_bf16.h>
#include <cstdint>
#include <cstddef>

#define N_NODES 16384
#define N_EDGES 524288
#define H_DIM   128
#define DIN     1024

using bf16 = __hip_bfloat16;

__device__ __forceinline__ float bf2f(bf16 v) { return __bfloat162float(v); }
// dtype-adaptive load, index in ELEMENTS (offset is dtype-independent)
__device__ __forceinline__ float ldv(const void* p, size_t i, int f32) {
    return f32 ? ((const float*)p)[i] : bf2f(((const bf16*)p)[i]);
}

// conv_lng is all-ones: fp32 word0 = 0x3F800000, bf16 pair = 0x3F803F80
__global__ void detect_k(const unsigned int* __restrict__ w, int* __restrict__ dtf) {
    if (threadIdx.x == 0) dtf[0] = (w[0] == 0x3F800000u) ? 1 : 0;
}

// ---------------------------------------------------------------- GEMM
// C[M,N] = act(A[M,K] @ W[K,N] + bias). A fp32 (a_f32=1) or adaptive input.
// W/bias adaptive (element offsets woff/boff). C fp32 or bf16 (OBF).
// ACT: 0=none 1=relu 2=tanh 3=sigmoid. 64x64x16 tiles, 256 thr, 4x4/thread.
template <int ACT, int OBF>
__global__ __launch_bounds__(256) void gemm_k(
    const void* __restrict__ A, int lda, int a_always_f32,
    const void* __restrict__ W, size_t woff,
    const void* __restrict__ bias, size_t boff,
    void* __restrict__ Cp, int ldc, int M, int N, int K,
    const int* __restrict__ dtf)
{
    const int f32 = dtf[0];
    const int af = (a_always_f32 != 0) || (f32 != 0);
    const int BM = 64, BN = 64, BK = 16;
    __shared__ float As[BK][BM + 1];
    __shared__ float Bs[BK][BN + 1];
    int tid = threadIdx.x;
    int tx = tid & 15, ty = tid >> 4;
    int row0 = blockIdx.y * BM, col0 = blockIdx.x * BN;
    float acc[4][4] = {};

    for (int k0 = 0; k0 < K; k0 += BK) {
        {
            int r = tid >> 2, kb = (tid & 3) * 4;
            size_t base = (size_t)(row0 + r) * lda + k0 + kb;
            #pragma unroll
            for (int i = 0; i < 4; i++) As[kb + i][r] = ldv(A, base + i, af);
        }
        {
            int kk = tid >> 4, cb = (tid & 15) * 4;
            size_t base = woff + (size_t)(k0 + kk) * N + col0 + cb;
            #pragma unroll
            for (int i = 0; i < 4; i++) Bs[kk][cb + i] = ldv(W, base + i, f32);
        }
        __syncthreads();
        #pragma unroll
        for (int kk = 0; kk < BK; kk++) {
            float a[4], b[4];
            #pragma unroll
            for (int i = 0; i < 4; i++) a[i] = As[kk][ty * 4 + i];
            #pragma unroll
            for (int j = 0; j < 4; j++) b[j] = Bs[kk][tx * 4 + j];
            #pragma unroll
            for (int i = 0; i < 4; i++)
                #pragma unroll
                for (int j = 0; j < 4; j++)
                    acc[i][j] = fmaf(a[i], b[j], acc[i][j]);
        }
        __syncthreads();
    }
    #pragma unroll
    for (int i = 0; i < 4; i++) {
        int r = row0 + ty * 4 + i;
        #pragma unroll
        for (int j = 0; j < 4; j++) {
            int c = col0 + tx * 4 + j;
            float v = acc[i][j] + ldv(bias, boff + c, f32);
            if (ACT == 1) v = fmaxf(v, 0.f);
            else if (ACT == 2) v = tanhf(v);
            else if (ACT == 3) v = 1.f / (1.f + __expf(-v));
            if (OBF) ((bf16*)Cp)[(size_t)r * ldc + c] = __float2bfloat16(v);
            else     ((float*)Cp)[(size_t)r * ldc + c] = v;
        }
    }
}

// ---------------------------------------------------------------- CSR build
__global__ void hist_k(const int* __restrict__ dst, int* __restrict__ deg, int E) {
    int e = blockIdx.x * blockDim.x + threadIdx.x;
    if (e < E) atomicAdd(&deg[dst[e]], 1);
}

// single wave, chunked serial scan — obviously race-free
__global__ __launch_bounds__(64) void scan_k(const int* __restrict__ deg,
                                             int* __restrict__ offs,
                                             int* __restrict__ cursor, int n) {
    __shared__ int part[64];
    int tid = threadIdx.x;
    int chunk = n / 64;
    int base = tid * chunk;
    int s = 0;
    for (int i = 0; i < chunk; i++) s += deg[base + i];
    part[tid] = s;
    __syncthreads();
    if (tid == 0) {
        int run = 0;
        for (int i = 0; i < 64; i++) { int v = part[i]; part[i] = run; run += v; }
        offs[n] = run;
    }
    __syncthreads();
    int run = part[tid];
    for (int i = 0; i < chunk; i++) {
        offs[base + i] = run;
        cursor[base + i] = run;
        run += deg[base + i];
    }
}

__global__ void scatter_k(const int* __restrict__ src, const int* __restrict__ dst,
                          const void* __restrict__ ew, const int* __restrict__ dtf,
                          int* __restrict__ cursor, int* __restrict__ csr_src,
                          float* __restrict__ csr_ew, int E) {
    int e = blockIdx.x * blockDim.x + threadIdx.x;
    if (e < E) {
        int f32 = dtf[0];
        int d = dst[e];
        int p = atomicAdd(&cursor[d], 1);
        csr_src[p] = src[e];
        csr_ew[p] = ldv(ew, e, f32);
    }
}

// ---------------------------------------------------------------- aggregation
// block (128 thr = channels) per node; two-pass softmax (no -inf arithmetic)
__global__ __launch_bounds__(128) void agg_k(
    const float* __restrict__ xin, int ldx,
    const int* __restrict__ offs, const int* __restrict__ csr_src,
    const float* __restrict__ csr_ew,
    const void* __restrict__ conv_t, int layer, const int* __restrict__ dtf,
    float* __restrict__ hout)
{
    int node = blockIdx.x, h = threadIdx.x;
    int f32 = dtf[0];
    float t = ldv(conv_t, layer, f32);
    int s0 = offs[node], s1 = offs[node + 1];
    float m = 0.f;   // ref: where(isfinite(segment_max), m, 0) -> empty = 0
    bool first = true;
    for (int p = s0; p < s1; p++) {
        float msg = fmaxf(xin[(size_t)csr_src[p] * ldx + h] + csr_ew[p], 0.f) + 1e-7f;
        float lg = msg * t;
        m = first ? lg : fmaxf(m, lg);
        first = false;
    }
    float ssum = 0.f, wsum = 0.f;
    for (int p = s0; p < s1; p++) {
        float msg = fmaxf(xin[(size_t)csr_src[p] * ldx + h] + csr_ew[p], 0.f) + 1e-7f;
        float e = __expf(msg * t - m);
        ssum += e;
        wsum += msg * e;
    }
    float agg = wsum / (ssum + 1e-16f);
    hout[(size_t)node * H_DIM + h] = agg + xin[(size_t)node * ldx + h];
}

// ---------------------------------------------------------------- LayerNorm
__global__ void ln_relu_k(const float* in, const void* __restrict__ g, size_t goff,
                          const void* __restrict__ b, size_t boff,
                          const int* __restrict__ dtf, float* out) {
    extern __shared__ float sd[];
    int C = blockDim.x, tid = threadIdx.x;
    int f32 = dtf[0];
    size_t base = (size_t)blockIdx.x * C;
    float v = in[base + tid];
    sd[tid] = v; __syncthreads();
    for (int s = C >> 1; s > 0; s >>= 1) { if (tid < s) sd[tid] += sd[tid + s]; __syncthreads(); }
    float mu = sd[0] / C; __syncthreads();
    float d = v - mu;
    sd[tid] = d * d; __syncthreads();
    for (int s = C >> 1; s > 0; s >>= 1) { if (tid < s) sd[tid] += sd[tid + s]; __syncthreads(); }
    float var = sd[0] / C;
    float y = d * rsqrtf(var + 1e-5f) * ldv(g, goff + tid, f32) + ldv(b, boff + tid, f32);
    out[base + tid] = fmaxf(y, 0.f);
}

__global__ __launch_bounds__(128) void ln_relu_res_k(
    const float* __restrict__ h2,
    const void* __restrict__ g, size_t goff,
    const void* __restrict__ b, size_t boff,
    const int* __restrict__ dtf,
    const float* __restrict__ xold, float* __restrict__ xnew) {
    __shared__ float sd[128];
    int tid = threadIdx.x, row = blockIdx.x;
    int f32 = dtf[0];
    float v = h2[(size_t)row * 128 + tid];
    sd[tid] = v; __syncthreads();
    for (int s = 64; s > 0; s >>= 1) { if (tid < s) sd[tid] += sd[tid + s]; __syncthreads(); }
    float mu = sd[0] / 128.f; __syncthreads();
    float d = v - mu;
    sd[tid] = d * d; __syncthreads();
    for (int s = 64; s > 0; s >>= 1) { if (tid < s) sd[tid] += sd[tid + s]; __syncthreads(); }
    float var = sd[0] / 128.f;
    float y = fmaxf(d * rsqrtf(var + 1e-5f) * ldv(g, goff + tid, f32) + ldv(b, boff + tid, f32), 0.f);
    xnew[(size_t)row * 512 + tid] = xold[(size_t)row * 512 + tid] + y;
}

// ---------------------------------------------------------------- attention
__global__ __launch_bounds__(64) void attn_A_k(const float* __restrict__ a,
                                               const bf16* __restrict__ bbuf,
                                               const void* __restrict__ wc,
                                               const void* __restrict__ bc,
                                               const int* __restrict__ dtf,
                                               float* __restrict__ A) {
    int row = blockIdx.x, lane = threadIdx.x;
    int f32 = dtf[0];
    const float* ar = a + (size_t)row * 512;
    const bf16* br = bbuf + (size_t)row * 512;
    float acc = 0.f;
    for (int j = lane; j < 512; j += 64) acc += ar[j] * bf2f(br[j]) * ldv(wc, j, f32);
    for (int s = 32; s > 0; s >>= 1) acc += __shfl_xor(acc, s, 64);
    if (lane == 0) A[row] = acc + ldv(bc, 0, f32);
}

__global__ __launch_bounds__(1024) void softmax_k(float* __restrict__ A, int n) {
    __shared__ float sd[1024];
    int tid = threadIdx.x;
    float mx = -3.4e38f;
    for (int i = tid; i < n; i += 1024) mx = fmaxf(mx, A[i]);
    sd[tid] = mx; __syncthreads();
    for (int s = 512; s > 0; s >>= 1) { if (tid < s) sd[tid] = fmaxf(sd[tid], sd[tid + s]); __syncthreads(); }
    float gmax = sd[0]; __syncthreads();
    float sum = 0.f;
    for (int i = tid; i < n; i += 1024) sum += __expf(A[i] - gmax);
    sd[tid] = sum; __syncthreads();
    for (int s = 512; s > 0; s >>= 1) { if (tid < s) sd[tid] += sd[tid + s]; __syncthreads(); }
    float inv = 1.f / sd[0];
    for (int i = tid; i < n; i += 1024) A[i] = __expf(A[i] - gmax) * inv;
}

__global__ __launch_bounds__(256) void pooled_k(const float* __restrict__ w,
                                                const float* __restrict__ hp,
                                                float* __restrict__ pooled,
                                                int rowsPerBlk) {
    int tid = threadIdx.x;
    int r0 = blockIdx.x * rowsPerBlk;
    float a0 = 0.f, a1 = 0.f;
    for (int r = 0; r < rowsPerBlk; r++) {
        int n = r0 + r;
        float wn = w[n];
        const float* hr = hp + (size_t)n * 512;
        a0 += wn * hr[tid];
        a1 += wn * hr[tid + 256];
    }
    atomicAdd(&pooled[tid], a0);
    atomicAdd(&pooled[tid + 256], a1);
}

__global__ __launch_bounds__(512) void final_k(const float* __restrict__ pooled,
                                               const void* __restrict__ rw,
                                               const void* __restrict__ rb,
                                               const void* __restrict__ cw,
                                               const void* __restrict__ cb,
                                               const int* __restrict__ dtf,
                                               void* __restrict__ out) {
    __shared__ float pl[512];
    __shared__ float vec[512];
    int tid = threadIdx.x;
    int f32 = dtf[0];
    pl[tid] = pooled[tid];
    __syncthreads();
    float acc = ldv(rb, tid, f32);
    for (int k = 0; k < 512; k++) acc = fmaf(pl[k], ldv(rw, (size_t)k * 512 + tid, f32), acc);
    vec[tid] = fmaxf(acc, 0.f);
    __syncthreads();
    if (tid < 3) {
        float o = ldv(cb, tid, f32);
        for (int j = 0; j < 512; j++) o += vec[j] * ldv(cw, (size_t)j * 3 + tid, f32);
        if (f32) ((float*)out)[tid] = o;
        else     ((bf16*)out)[tid] = __float2bfloat16(o);
    }
}

// ---------------------------------------------------------------- launcher
extern "C" void kernel_launch(void* const* d_in, const int* in_sizes, int n_in,
                              void* d_out, int out_size, void* d_ws, size_t ws_size,
                              hipStream_t stream) {
    const void* features = d_in[0];
    const int*  eidx     = (const int*)d_in[1];
    const void* ew       = d_in[2];
    const void* fc_w     = d_in[3];
    const void* fc_b     = d_in[4];
    const void* conv_w1  = d_in[5];
    const void* conv_b1  = d_in[6];
    const void* conv_lng = d_in[7];
    const void* conv_lnb = d_in[8];
    const void* conv_w2  = d_in[9];
    const void* conv_b2  = d_in[10];
    const void* conv_t   = d_in[11];
    const void* blk_lng  = d_in[12];
    const void* blk_lnb  = d_in[13];
    const void* phi_w    = d_in[14];
    const void* phi_b    = d_in[15];
    const void* attn_wa  = d_in[16];
    const void* attn_ba  = d_in[17];
    const void* attn_wb  = d_in[18];
    const void* attn_bb  = d_in[19];
    const void* attn_wc  = d_in[20];
    const void* attn_bc  = d_in[21];
    const void* rho_w    = d_in[22];
    const void* rho_b    = d_in[23];
    const void* clf_w    = d_in[24];
    const void* clf_b    = d_in[25];

    const int* src = eidx;
    const int* dst = eidx + N_EDGES;

    // bump allocator — smalls FIRST; total ~92.3 MiB (was 139: suspected ws overflow)
    char* wsp = (char*)d_ws;
    size_t off = 0;
    auto alloc = [&](size_t bytes) -> void* {
        void* p = wsp + off;
        off = (off + bytes + 255) & ~(size_t)255;
        return p;
    };
    int*   dtf    = (int*)alloc(256);
    int*   deg    = (int*)alloc((size_t)N_NODES * 4);
    int*   offs   = (int*)alloc((size_t)(N_NODES + 1) * 4);
    int*   cursor = (int*)alloc((size_t)N_NODES * 4);
    float* Aw     = (float*)alloc((size_t)N_NODES * 4);
    float* pooled = (float*)alloc(512 * 4);
    int*   csr_src= (int*)alloc((size_t)N_EDGES * 4);
    float* csr_ew = (float*)alloc((size_t)N_EDGES * 4);
    float* x_cat  = (float*)alloc((size_t)N_NODES * 512 * 4);   // 32 MiB
    char*  scratch= (char*)alloc((size_t)N_NODES * 384 * 4);    // 24 MiB
    float* hp     = (float*)alloc((size_t)N_NODES * 512 * 4);   // 32 MiB

    float* h_tmp = (float*)scratch;                               // [N,128] fp32
    float* mid   = (float*)(scratch + (size_t)N_NODES * 128 * 4); // [N,256] fp32
    float* h2    = h_tmp;          // conv2-out reuses agg buffer (dead by then)
    float* a_buf = x_cat;          // x_cat free after phi gemm
    bf16*  b_buf = (bf16*)scratch; // [N,512] bf16 = 16 MiB, convs done by then

    detect_k<<<1, 64, 0, stream>>>((const unsigned int*)conv_lng, dtf);

    // ---- CSR build
    hipMemsetAsync(deg, 0, (size_t)N_NODES * 4, stream);
    hist_k<<<N_EDGES / 256, 256, 0, stream>>>(dst, deg, N_EDGES);
    scan_k<<<1, 64, 0, stream>>>(deg, offs, cursor, N_NODES);
    scatter_k<<<N_EDGES / 256, 256, 0, stream>>>(src, dst, ew, dtf, cursor, csr_src, csr_ew, N_EDGES);

    // ---- fc: x0 = relu(features @ fc_w + fc_b) -> x_cat[:, 0:128]
    gemm_k<1, 0><<<dim3(2, 256), 256, 0, stream>>>(
        features, DIN, 0, fc_w, 0, fc_b, 0, x_cat, 512, N_NODES, 128, DIN, dtf);

    // ---- 3 GENConv layers
    for (int l = 0; l < 3; l++) {
        const float* x_in = x_cat + (size_t)l * 128;   // ld 512
        agg_k<<<N_NODES, 128, 0, stream>>>(x_in, 512, offs, csr_src, csr_ew, conv_t, l, dtf, h_tmp);
        gemm_k<0, 0><<<dim3(4, 256), 256, 0, stream>>>(
            h_tmp, 128, 1, conv_w1, (size_t)l * 128 * 256, conv_b1, (size_t)l * 256,
            mid, 256, N_NODES, 256, 128, dtf);
        ln_relu_k<<<N_NODES, 256, 256 * 4, stream>>>(
            mid, conv_lng, (size_t)l * 256, conv_lnb, (size_t)l * 256, dtf, mid);
        if (l == 0) {
            gemm_k<0, 0><<<dim3(2, 256), 256, 0, stream>>>(
                mid, 256, 1, conv_w2, (size_t)l * 256 * 128, conv_b2, (size_t)l * 128,
                x_cat + 128, 512, N_NODES, 128, 256, dtf);
        } else {
            gemm_k<0, 0><<<dim3(2, 256), 256, 0, stream>>>(
                mid, 256, 1, conv_w2, (size_t)l * 256 * 128, conv_b2, (size_t)l * 128,
                h2, 128, N_NODES, 128, 256, dtf);
            ln_relu_res_k<<<N_NODES, 128, 0, stream>>>(
                h2, blk_lng, (size_t)l * 128, blk_lnb, (size_t)l * 128, dtf,
                x_cat + (size_t)l * 128, x_cat + (size_t)(l + 1) * 128);
        }
    }

    // ---- pooling head
    gemm_k<1, 0><<<dim3(8, 256), 256, 0, stream>>>(
        x_cat, 512, 1, phi_w, 0, phi_b, 0, hp, 512, N_NODES, 512, 512, dtf);
    gemm_k<2, 0><<<dim3(8, 256), 256, 0, stream>>>(
        hp, 512, 1, attn_wa, 0, attn_ba, 0, a_buf, 512, N_NODES, 512, 512, dtf);
    gemm_k<3, 1><<<dim3(8, 256), 256, 0, stream>>>(
        hp, 512, 1, attn_wb, 0, attn_bb, 0, b_buf, 512, N_NODES, 512, 512, dtf);
    attn_A_k<<<N_NODES, 64, 0, stream>>>(a_buf, b_buf, attn_wc, attn_bc, dtf, Aw);
    softmax_k<<<1, 1024, 0, stream>>>(Aw, N_NODES);
    hipMemsetAsync(pooled, 0, 512 * 4, stream);
    pooled_k<<<128, 256, 0, stream>>>(Aw, hp, pooled, N_NODES / 128);
    final_k<<<1, 512, 0, stream>>>(pooled, rho_w, rho_b, clf_w, clf_b, dtf, d_out);
}

// Round 3
// 909.729 us; speedup vs baseline: 2.2219x; 2.2219x over previous
//
#include <hip/hip_runtime.h>
#include <hip/hip_bf16.h>
#include <cstdint>
#include <cstddef>

#define N_NODES 16384
#define N_EDGES 524288

using bf16 = __hip_bfloat16;
typedef short bf16x8 __attribute__((ext_vector_type(8)));
typedef float f32x4 __attribute__((ext_vector_type(4)));

__device__ __forceinline__ float bf2f(bf16 v) { return __bfloat162float(v); }
// dtype-adaptive load, index in ELEMENTS
__device__ __forceinline__ float ldv(const void* p, size_t i, int f32) {
    return f32 ? ((const float*)p)[i] : bf2f(((const bf16*)p)[i]);
}

// conv_lng is all-ones: fp32 word0 = 0x3F800000, bf16 pair = 0x3F803F80
__global__ void detect_k(const unsigned int* __restrict__ w, int* __restrict__ dtf) {
    if (threadIdx.x == 0) dtf[0] = (w[0] == 0x3F800000u) ? 1 : 0;
}

// features fp32 -> bf16 (no-op when inputs already bf16)
__global__ void conv_feat_k(const float* __restrict__ in, bf16* __restrict__ out,
                            const int* __restrict__ dtf, int n) {
    if (!dtf[0]) return;
    for (int i = blockIdx.x * blockDim.x + threadIdx.x; i < n; i += gridDim.x * blockDim.x)
        out[i] = __float2bfloat16(in[i]);
}

// W[K,N] (element offset woff, adaptive dtype) -> WT[N,K] bf16
__global__ void transp_k(const void* __restrict__ W, size_t woff, bf16* __restrict__ WT,
                         int K, int N, const int* __restrict__ dtf) {
    int f32 = dtf[0];
    int i = blockIdx.x * blockDim.x + threadIdx.x;
    if (i >= N * K) return;
    int n = i / K, k = i % K;
    WT[i] = __float2bfloat16(ldv(W, woff + (size_t)k * N + n, f32));
}

// ---------------------------------------------------------------- MFMA GEMM
// C[M,N] = act(A[M,K] @ WT^T + bias); A bf16 [M,K] lda, WT bf16 [N,K],
// C bf16 ldc. 64x64 tile per 1-wave block, BK=32, 16x16x32 bf16 MFMA.
// ACT: 0=none 1=relu 2=tanh 3=sigmoid
#define GLD(gp, lp) __builtin_amdgcn_global_load_lds( \
    (const __attribute__((address_space(1))) void*)(gp), \
    (__attribute__((address_space(3))) void*)(lp), 16, 0, 0)

template <int ACT>
__global__ __launch_bounds__(64) void mgemm_k(
    const bf16* __restrict__ A, const bf16* __restrict__ Aalt, int sel, int lda,
    const bf16* __restrict__ WT,
    const void* __restrict__ bias, size_t boff,
    bf16* __restrict__ C, int ldc, int K, const int* __restrict__ dtf)
{
    __shared__ unsigned short lA[64 * 32];   // [row][k] rows of 64B — no padding (GLD order)
    __shared__ unsigned short lB[64 * 32];   // [n][k]
    const int f32 = dtf[0];
    const bf16* Ap = (sel && f32) ? Aalt : A;
    int lane = threadIdx.x;
    int row0 = blockIdx.y * 64, col0 = blockIdx.x * 64;
    const bf16* Ag = Ap + (size_t)row0 * lda;
    const bf16* Bg = WT + (size_t)col0 * K;

    f32x4 acc[4][4] = {};
    int sr = lane >> 2, skc = lane & 3;      // staging: 4 lanes per 64B row
    int fr = lane & 15, fg = lane >> 4;      // fragment row/col + k-group

    for (int k0 = 0; k0 < K; k0 += 32) {
        #pragma unroll
        for (int j = 0; j < 4; j++) {
            GLD(Ag + (size_t)(j * 16 + sr) * lda + k0 + skc * 8, (char*)lA + j * 1024);
            GLD(Bg + (size_t)(j * 16 + sr) * K   + k0 + skc * 8, (char*)lB + j * 1024);
        }
        __syncthreads();
        bf16x8 aF[4], bF[4];
        #pragma unroll
        for (int i = 0; i < 4; i++) {
            aF[i] = *(const bf16x8*)&lA[(i * 16 + fr) * 32 + fg * 8];
            bF[i] = *(const bf16x8*)&lB[(i * 16 + fr) * 32 + fg * 8];
        }
        #pragma unroll
        for (int i = 0; i < 4; i++)
            #pragma unroll
            for (int j = 0; j < 4; j++)
                acc[i][j] = __builtin_amdgcn_mfma_f32_16x16x32_bf16(aF[i], bF[j], acc[i][j], 0, 0, 0);
        __syncthreads();
    }
    // epilogue: C/D layout col=lane&15, row=(lane>>4)*4+reg [m89-verified]
    #pragma unroll
    for (int j = 0; j < 4; j++) {
        int col = col0 + j * 16 + fr;
        float bv = ldv(bias, boff + col, f32);
        #pragma unroll
        for (int i = 0; i < 4; i++) {
            #pragma unroll
            for (int rr = 0; rr < 4; rr++) {
                int row = row0 + i * 16 + fg * 4 + rr;
                float v = acc[i][j][rr] + bv;
                if (ACT == 1) v = fmaxf(v, 0.f);
                else if (ACT == 2) v = tanhf(v);
                else if (ACT == 3) v = 1.f / (1.f + __expf(-v));
                C[(size_t)row * ldc + col] = __float2bfloat16(v);
            }
        }
    }
}

// ---------------------------------------------------------------- CSR build
__global__ void hist_k(const int* __restrict__ dst, int* __restrict__ deg, int E) {
    int e = blockIdx.x * blockDim.x + threadIdx.x;
    if (e < E) atomicAdd(&deg[dst[e]], 1);
}

__global__ __launch_bounds__(64) void scan_k(const int* __restrict__ deg,
                                             int* __restrict__ offs,
                                             int* __restrict__ cursor, int n) {
    __shared__ int part[64];
    int tid = threadIdx.x;
    int chunk = n / 64;
    int base = tid * chunk;
    int s = 0;
    for (int i = 0; i < chunk; i++) s += deg[base + i];
    part[tid] = s;
    __syncthreads();
    if (tid == 0) {
        int run = 0;
        for (int i = 0; i < 64; i++) { int v = part[i]; part[i] = run; run += v; }
        offs[n] = run;
    }
    __syncthreads();
    int run = part[tid];
    for (int i = 0; i < chunk; i++) {
        offs[base + i] = run;
        cursor[base + i] = run;
        run += deg[base + i];
    }
}

__global__ void scatter_k(const int* __restrict__ src, const int* __restrict__ dst,
                          const void* __restrict__ ew, const int* __restrict__ dtf,
                          int* __restrict__ cursor, int* __restrict__ csr_src,
                          float* __restrict__ csr_ew, int E) {
    int e = blockIdx.x * blockDim.x + threadIdx.x;
    if (e < E) {
        int f32 = dtf[0];
        int d = dst[e];
        int p = atomicAdd(&cursor[d], 1);
        csr_src[p] = src[e];
        csr_ew[p] = ldv(ew, e, f32);
    }
}

// ---------------------------------------------------------------- aggregation
// block (128 thr = channels) per node; single-pass online softmax
__global__ __launch_bounds__(128) void agg_k(
    const bf16* __restrict__ xin, int ldx,
    const int* __restrict__ offs, const int* __restrict__ csr_src,
    const float* __restrict__ csr_ew,
    const void* __restrict__ conv_t, int layer, const int* __restrict__ dtf,
    bf16* __restrict__ hout)
{
    int node = blockIdx.x, h = threadIdx.x;
    int f32 = dtf[0];
    float t = ldv(conv_t, layer, f32);
    int s0 = offs[node], s1 = offs[node + 1];
    float m = -INFINITY, ssum = 0.f, wsum = 0.f;
    for (int p = s0; p < s1; p++) {
        float xv = bf2f(xin[(size_t)csr_src[p] * ldx + h]);
        float msg = fmaxf(xv + csr_ew[p], 0.f) + 1e-7f;
        float lg = msg * t;                 // always finite (msg>0, t finite)
        float mn = fmaxf(m, lg);
        float sc = __expf(m - mn);          // first iter: exp(-inf)=0
        float el = __expf(lg - mn);
        ssum = ssum * sc + el;
        wsum = wsum * sc + msg * el;
        m = mn;
    }
    float agg = wsum / (ssum + 1e-16f);
    hout[(size_t)node * 128 + h] =
        __float2bfloat16(agg + bf2f(xin[(size_t)node * ldx + h]));
}

// ---------------------------------------------------------------- LayerNorm
__global__ void ln_relu_k(const bf16* in, const void* __restrict__ g, size_t goff,
                          const void* __restrict__ b, size_t boff,
                          const int* __restrict__ dtf, bf16* out) {
    extern __shared__ float sd[];
    int C = blockDim.x, tid = threadIdx.x;
    int f32 = dtf[0];
    size_t base = (size_t)blockIdx.x * C;
    float v = bf2f(in[base + tid]);
    sd[tid] = v; __syncthreads();
    for (int s = C >> 1; s > 0; s >>= 1) { if (tid < s) sd[tid] += sd[tid + s]; __syncthreads(); }
    float mu = sd[0] / C; __syncthreads();
    float d = v - mu;
    sd[tid] = d * d; __syncthreads();
    for (int s = C >> 1; s > 0; s >>= 1) { if (tid < s) sd[tid] += sd[tid + s]; __syncthreads(); }
    float var = sd[0] / C;
    float y = d * rsqrtf(var + 1e-5f) * ldv(g, goff + tid, f32) + ldv(b, boff + tid, f32);
    out[base + tid] = __float2bfloat16(fmaxf(y, 0.f));
}

// xnew[.,slice of 512] = xold[.,slice] + relu(LN(h2)*g+b), C=128
__global__ __launch_bounds__(128) void ln_relu_res_k(
    const bf16* __restrict__ h2,
    const void* __restrict__ g, size_t goff,
    const void* __restrict__ b, size_t boff,
    const int* __restrict__ dtf,
    const bf16* __restrict__ xold, bf16* __restrict__ xnew) {
    __shared__ float sd[128];
    int tid = threadIdx.x, row = blockIdx.x;
    int f32 = dtf[0];
    float v = bf2f(h2[(size_t)row * 128 + tid]);
    sd[tid] = v; __syncthreads();
    for (int s = 64; s > 0; s >>= 1) { if (tid < s) sd[tid] += sd[tid + s]; __syncthreads(); }
    float mu = sd[0] / 128.f; __syncthreads();
    float d = v - mu;
    sd[tid] = d * d; __syncthreads();
    for (int s = 64; s > 0; s >>= 1) { if (tid < s) sd[tid] += sd[tid + s]; __syncthreads(); }
    float var = sd[0] / 128.f;
    float y = fmaxf(d * rsqrtf(var + 1e-5f) * ldv(g, goff + tid, f32) + ldv(b, boff + tid, f32), 0.f);
    xnew[(size_t)row * 512 + tid] =
        __float2bfloat16(bf2f(xold[(size_t)row * 512 + tid]) + y);
}

// ---------------------------------------------------------------- attention
__global__ __launch_bounds__(64) void attn_A_k(const bf16* __restrict__ a,
                                               const bf16* __restrict__ bbuf,
                                               const void* __restrict__ wc,
                                               const void* __restrict__ bc,
                                               const int* __restrict__ dtf,
                                               float* __restrict__ A) {
    int row = blockIdx.x, lane = threadIdx.x;
    int f32 = dtf[0];
    const bf16* ar = a + (size_t)row * 512;
    const bf16* br = bbuf + (size_t)row * 512;
    float acc = 0.f;
    for (int j = lane; j < 512; j += 64) acc += bf2f(ar[j]) * bf2f(br[j]) * ldv(wc, j, f32);
    for (int s = 32; s > 0; s >>= 1) acc += __shfl_xor(acc, s, 64);
    if (lane == 0) A[row] = acc + ldv(bc, 0, f32);
}

__global__ __launch_bounds__(1024) void softmax_k(float* __restrict__ A, int n) {
    __shared__ float sd[1024];
    int tid = threadIdx.x;
    float mx = -3.4e38f;
    for (int i = tid; i < n; i += 1024) mx = fmaxf(mx, A[i]);
    sd[tid] = mx; __syncthreads();
    for (int s = 512; s > 0; s >>= 1) { if (tid < s) sd[tid] = fmaxf(sd[tid], sd[tid + s]); __syncthreads(); }
    float gmax = sd[0]; __syncthreads();
    float sum = 0.f;
    for (int i = tid; i < n; i += 1024) sum += __expf(A[i] - gmax);
    sd[tid] = sum; __syncthreads();
    for (int s = 512; s > 0; s >>= 1) { if (tid < s) sd[tid] += sd[tid + s]; __syncthreads(); }
    float inv = 1.f / sd[0];
    for (int i = tid; i < n; i += 1024) A[i] = __expf(A[i] - gmax) * inv;
}

__global__ __launch_bounds__(256) void pooled_k(const float* __restrict__ w,
                                                const bf16* __restrict__ hp,
                                                float* __restrict__ pooled,
                                                int rowsPerBlk) {
    int tid = threadIdx.x;
    int r0 = blockIdx.x * rowsPerBlk;
    float a0 = 0.f, a1 = 0.f;
    for (int r = 0; r < rowsPerBlk; r++) {
        int n = r0 + r;
        float wn = w[n];
        const bf16* hr = hp + (size_t)n * 512;
        a0 += wn * bf2f(hr[tid]);
        a1 += wn * bf2f(hr[tid + 256]);
    }
    atomicAdd(&pooled[tid], a0);
    atomicAdd(&pooled[tid + 256], a1);
}

__global__ __launch_bounds__(512) void final_k(const float* __restrict__ pooled,
                                               const void* __restrict__ rw,
                                               const void* __restrict__ rb,
                                               const void* __restrict__ cw,
                                               const void* __restrict__ cb,
                                               const int* __restrict__ dtf,
                                               void* __restrict__ out) {
    __shared__ float pl[512];
    __shared__ float vec[512];
    int tid = threadIdx.x;
    int f32 = dtf[0];
    pl[tid] = pooled[tid];
    __syncthreads();
    float acc = ldv(rb, tid, f32);
    for (int k = 0; k < 512; k++) acc = fmaf(pl[k], ldv(rw, (size_t)k * 512 + tid, f32), acc);
    vec[tid] = fmaxf(acc, 0.f);
    __syncthreads();
    if (tid < 3) {
        float o = ldv(cb, tid, f32);
        for (int j = 0; j < 512; j++) o += vec[j] * ldv(cw, (size_t)j * 3 + tid, f32);
        if (f32) ((float*)out)[tid] = o;
        else     ((bf16*)out)[tid] = __float2bfloat16(o);
    }
}

// ---------------------------------------------------------------- launcher
extern "C" void kernel_launch(void* const* d_in, const int* in_sizes, int n_in,
                              void* d_out, int out_size, void* d_ws, size_t ws_size,
                              hipStream_t stream) {
    const void* features = d_in[0];
    const int*  eidx     = (const int*)d_in[1];
    const void* ew       = d_in[2];
    const void* fc_w     = d_in[3];
    const void* fc_b     = d_in[4];
    const void* conv_w1  = d_in[5];
    const void* conv_b1  = d_in[6];
    const void* conv_lng = d_in[7];
    const void* conv_lnb = d_in[8];
    const void* conv_w2  = d_in[9];
    const void* conv_b2  = d_in[10];
    const void* conv_t   = d_in[11];
    const void* blk_lng  = d_in[12];
    const void* blk_lnb  = d_in[13];
    const void* phi_w    = d_in[14];
    const void* phi_b    = d_in[15];
    const void* attn_wa  = d_in[16];
    const void* attn_ba  = d_in[17];
    const void* attn_wb  = d_in[18];
    const void* attn_bb  = d_in[19];
    const void* attn_wc  = d_in[20];
    const void* attn_bc  = d_in[21];
    const void* rho_w    = d_in[22];
    const void* rho_b    = d_in[23];
    const void* clf_w    = d_in[24];
    const void* clf_b    = d_in[25];

    const int* src = eidx;
    const int* dst = eidx + N_EDGES;

    char* wsp = (char*)d_ws;
    size_t off = 0;
    auto alloc = [&](size_t bytes) -> void* {
        void* p = wsp + off;
        off = (off + bytes + 255) & ~(size_t)255;
        return p;
    };
    int*   dtf    = (int*)alloc(256);
    int*   deg    = (int*)alloc((size_t)N_NODES * 4);
    int*   offs   = (int*)alloc((size_t)(N_NODES + 1) * 4);
    int*   cursor = (int*)alloc((size_t)N_NODES * 4);
    float* Aw     = (float*)alloc((size_t)N_NODES * 4);
    float* pooled = (float*)alloc(512 * 4);
    int*   csr_src= (int*)alloc((size_t)N_EDGES * 4);
    float* csr_ew = (float*)alloc((size_t)N_EDGES * 4);
    // transposed bf16 weights
    bf16* WT_fc  = (bf16*)alloc((size_t)128 * 1024 * 2);
    bf16* WT_c1  = (bf16*)alloc((size_t)3 * 256 * 128 * 2);
    bf16* WT_c2  = (bf16*)alloc((size_t)3 * 128 * 256 * 2);
    bf16* WT_phi = (bf16*)alloc((size_t)512 * 512 * 2);
    bf16* WT_wa  = (bf16*)alloc((size_t)512 * 512 * 2);
    bf16* WT_wb  = (bf16*)alloc((size_t)512 * 512 * 2);
    // activations (bf16)
    bf16* x_cat   = (bf16*)alloc((size_t)N_NODES * 512 * 2);  // 16 MiB
    bf16* scratch = (bf16*)alloc((size_t)N_NODES * 512 * 2);  // 16 MiB
    bf16* hp      = (bf16*)alloc((size_t)N_NODES * 512 * 2);  // 16 MiB
    bf16* feat_bf = (bf16*)alloc((size_t)N_NODES * 1024 * 2); // 32 MiB

    bf16* h_tmp = scratch;                       // [N,128]
    bf16* mid   = scratch + (size_t)N_NODES * 128; // [N,256]
    bf16* h2    = h_tmp;                         // reuse (agg result dead)
    bf16* b_buf = scratch;                       // [N,512] after convs done
    bf16* a_buf = feat_bf;                       // [N,512] after fc done

    detect_k<<<1, 64, 0, stream>>>((const unsigned int*)conv_lng, dtf);
    conv_feat_k<<<4096, 256, 0, stream>>>((const float*)features, feat_bf, dtf, N_NODES * 1024);

    // weight transposes -> [N,K] bf16
    transp_k<<<(128 * 1024 + 255) / 256, 256, 0, stream>>>(fc_w, 0, WT_fc, 1024, 128, dtf);
    for (int l = 0; l < 3; l++) {
        transp_k<<<(256 * 128 + 255) / 256, 256, 0, stream>>>(
            conv_w1, (size_t)l * 128 * 256, WT_c1 + (size_t)l * 256 * 128, 128, 256, dtf);
        transp_k<<<(128 * 256 + 255) / 256, 256, 0, stream>>>(
            conv_w2, (size_t)l * 256 * 128, WT_c2 + (size_t)l * 128 * 256, 256, 128, dtf);
    }
    transp_k<<<(512 * 512 + 255) / 256, 256, 0, stream>>>(phi_w, 0, WT_phi, 512, 512, dtf);
    transp_k<<<(512 * 512 + 255) / 256, 256, 0, stream>>>(attn_wa, 0, WT_wa, 512, 512, dtf);
    transp_k<<<(512 * 512 + 255) / 256, 256, 0, stream>>>(attn_wb, 0, WT_wb, 512, 512, dtf);

    // CSR build
    hipMemsetAsync(deg, 0, (size_t)N_NODES * 4, stream);
    hist_k<<<N_EDGES / 256, 256, 0, stream>>>(dst, deg, N_EDGES);
    scan_k<<<1, 64, 0, stream>>>(deg, offs, cursor, N_NODES);
    scatter_k<<<N_EDGES / 256, 256, 0, stream>>>(src, dst, ew, dtf, cursor, csr_src, csr_ew, N_EDGES);

    // fc: x0 = relu(features @ fc_w + fc_b) -> x_cat[:, 0:128]
    mgemm_k<1><<<dim3(2, 256), 64, 0, stream>>>(
        (const bf16*)features, feat_bf, 1, 1024, WT_fc, fc_b, 0, x_cat, 512, 1024, dtf);

    // 3 GENConv layers
    for (int l = 0; l < 3; l++) {
        const bf16* x_in = x_cat + (size_t)l * 128;   // ld 512
        agg_k<<<N_NODES, 128, 0, stream>>>(x_in, 512, offs, csr_src, csr_ew, conv_t, l, dtf, h_tmp);
        mgemm_k<0><<<dim3(4, 256), 64, 0, stream>>>(
            h_tmp, h_tmp, 0, 128, WT_c1 + (size_t)l * 256 * 128,
            conv_b1, (size_t)l * 256, mid, 256, 128, dtf);
        ln_relu_k<<<N_NODES, 256, 256 * 4, stream>>>(
            mid, conv_lng, (size_t)l * 256, conv_lnb, (size_t)l * 256, dtf, mid);
        if (l == 0) {
            mgemm_k<0><<<dim3(2, 256), 64, 0, stream>>>(
                mid, mid, 0, 256, WT_c2 + (size_t)l * 128 * 256,
                conv_b2, (size_t)l * 128, x_cat + 128, 512, 256, dtf);
        } else {
            mgemm_k<0><<<dim3(2, 256), 64, 0, stream>>>(
                mid, mid, 0, 256, WT_c2 + (size_t)l * 128 * 256,
                conv_b2, (size_t)l * 128, h2, 128, 256, dtf);
            ln_relu_res_k<<<N_NODES, 128, 0, stream>>>(
                h2, blk_lng, (size_t)l * 128, blk_lnb, (size_t)l * 128, dtf,
                x_cat + (size_t)l * 128, x_cat + (size_t)(l + 1) * 128);
        }
    }

    // pooling head
    mgemm_k<1><<<dim3(8, 256), 64, 0, stream>>>(
        x_cat, x_cat, 0, 512, WT_phi, phi_b, 0, hp, 512, 512, dtf);
    mgemm_k<2><<<dim3(8, 256), 64, 0, stream>>>(
        hp, hp, 0, 512, WT_wa, attn_ba, 0, a_buf, 512, 512, dtf);
    mgemm_k<3><<<dim3(8, 256), 64, 0, stream>>>(
        hp, hp, 0, 512, WT_wb, attn_bb, 0, b_buf, 512, 512, dtf);
    attn_A_k<<<N_NODES, 64, 0, stream>>>(a_buf, b_buf, attn_wc, attn_bc, dtf, Aw);
    softmax_k<<<1, 1024, 0, stream>>>(Aw, N_NODES);
    hipMemsetAsync(pooled, 0, 512 * 4, stream);
    pooled_k<<<128, 256, 0, stream>>>(Aw, hp, pooled, N_NODES / 128);
    final_k<<<1, 512, 0, stream>>>(pooled, rho_w, rho_b, clf_w, clf_b, dtf, d_out);
}